// Round 4
// baseline (353.437 us; speedup 1.0000x reference)
//
#include <hip/hip_runtime.h>
#include <hip/hip_bf16.h>
#include <stdint.h>

// ResNetV1 sparse conv block, MI355X (gfx950).
// out = relu( conv(relu(conv(x,W0)), W1) + x ),  conv[n,d] = sum_k sum_c x[idx[n,k],c] * W[k,c,d]
// N=150000, K=27, C=64.
// R4: register-pipelined, barrier-free, LDS-free conv.
//   - A fragments double-buffered in regs (aP/aQ): gather k+1 while k's MFMAs run.
//   - Neighbor indices ping-pong prefetched 2 ahead (giA/giB).
//   - Load ORDER per iter: b (this k) -> idx (k+2) -> gathers (k+1) -> MFMA.
//     vmcnt is ordered, so waiting on b leaves the younger gathers in flight.
//   - __launch_bounds__(64,2): ~184 unified regs, no spills (R2: spills = +270MB WRITE_SIZE).

typedef __attribute__((ext_vector_type(8))) short short8;
typedef __attribute__((ext_vector_type(4))) float f32x4;

#define NV 150000
#define KOFF 27

static __device__ __forceinline__ ushort f2bf(float f) {
  union { float f; uint32_t u; } v; v.f = f;
  uint32_t u = v.u;
  return (ushort)((u + 0x7fffu + ((u >> 16) & 1u)) >> 16);
}

__global__ void cvt_x_kernel(const float* __restrict__ x, ushort* __restrict__ xb, int n) {
  int i = blockIdx.x * 256 + threadIdx.x;
  if (i * 4 >= n) return;
  float4 v = ((const float4*)x)[i];
  ushort4 o;
  o.x = f2bf(v.x); o.y = f2bf(v.y); o.z = f2bf(v.z); o.w = f2bf(v.w);
  ((ushort4*)xb)[i] = o;
}

// Pack W [27][64][64] fp32 -> bf16 B-fragment order:
// flat = (((k*2+s)*4+ct)*64 + lane)*8 + j  <-  W[k][c=s*32+(lane>>4)*8+j][d=ct*16+(lane&15)]
__global__ void pack_w_kernel(const float* __restrict__ W, ushort* __restrict__ wp, int total) {
  int o = blockIdx.x * 256 + threadIdx.x;
  if (o >= total) return;
  int j  = o & 7;
  int l  = (o >> 3) & 63;
  int ct = (o >> 9) & 3;
  int s  = (o >> 11) & 1;
  int k  = o >> 12;
  int c  = s * 32 + (l >> 4) * 8 + j;
  int d  = ct * 16 + (l & 15);
  wp[o] = f2bf(W[(k * 64 + c) * 64 + d]);
}

template <int MODE>
struct ConvHelpers;

// One wave per 64 rows (4 x 16-row MFMA tiles).
// MODE 0: relu(conv) -> bf16. MODE 1: relu(conv+resid) -> fp32.
template <int MODE>
__global__ __launch_bounds__(64, 2) void conv_kernel(
    const ushort* __restrict__ feat,   // [N,64] bf16 bits
    const int*    __restrict__ nbr,    // [N,27]
    const ushort* __restrict__ wp,     // packed W, 27*4096 bf16
    const float*  __restrict__ resid,  // [N,64] fp32 (MODE 1)
    ushort*       __restrict__ out_bf, // MODE 0
    float*        __restrict__ out_f,  // MODE 1
    int n) {
  const int lane = threadIdx.x;       // 0..63
  const int quad = lane >> 4;
  const int lo   = lane & 15;
  const int mw   = blockIdx.x * 64;

  int roff[4];
  #pragma unroll
  for (int rt = 0; rt < 4; ++rt) {
    int r = mw + rt * 16 + lo;
    r = r < n ? r : n - 1;
    roff[rt] = r * KOFF;
  }

  const short8* wv = (const short8*)wp;  // frag t of offset k: wv[k*512 + t*64 + lane]

  f32x4 acc[4][4];
  #pragma unroll
  for (int rt = 0; rt < 4; ++rt)
    #pragma unroll
    for (int ct = 0; ct < 4; ++ct)
      acc[rt][ct] = (f32x4)0.0f;

  short8 aP[4][2], aQ[4][2];
  int giA[4], giB[4];

  // Prologue: idx k=0 -> gather aP(k=0); prefetch idx k=1.
  #pragma unroll
  for (int rt = 0; rt < 4; ++rt) giA[rt] = nbr[roff[rt]];
  #pragma unroll
  for (int rt = 0; rt < 4; ++rt) {
    const ushort* rowp = feat + giA[rt] * 64 + quad * 8;
    aP[rt][0] = *(const short8*)(rowp);
    aP[rt][1] = *(const short8*)(rowp + 32);
  }
  #pragma unroll
  for (int rt = 0; rt < 4; ++rt) giB[rt] = nbr[roff[rt] + 1];

  // 13 pairs handle k=0..25; tail handles k=26.
  #pragma unroll 1
  for (int k = 0; k < 26; k += 2) {
    // ---- even phase: consume aP(k); gather aQ(k+1) via giB; prefetch giA(k+2) ----
    {
      short8 b[8];
      #pragma unroll
      for (int t = 0; t < 8; ++t) b[t] = wv[k * 512 + t * 64 + lane];   // oldest loads
      #pragma unroll
      for (int rt = 0; rt < 4; ++rt) {
        const ushort* rowp = feat + giB[rt] * 64 + quad * 8;
        aQ[rt][0] = *(const short8*)(rowp);
        aQ[rt][1] = *(const short8*)(rowp + 32);
      }
      #pragma unroll
      for (int rt = 0; rt < 4; ++rt) giA[rt] = nbr[roff[rt] + k + 2];   // youngest
      #pragma unroll
      for (int s = 0; s < 2; ++s)
        #pragma unroll
        for (int rt = 0; rt < 4; ++rt)
          #pragma unroll
          for (int ct = 0; ct < 4; ++ct)
            acc[rt][ct] = __builtin_amdgcn_mfma_f32_16x16x32_bf16(aP[rt][s], b[s * 4 + ct], acc[rt][ct], 0, 0, 0);
    }
    // ---- odd phase: consume aQ(k+1); gather aP(k+2) via giA; prefetch giB(k+3) ----
    {
      short8 b[8];
      #pragma unroll
      for (int t = 0; t < 8; ++t) b[t] = wv[(k + 1) * 512 + t * 64 + lane];
      #pragma unroll
      for (int rt = 0; rt < 4; ++rt) {
        const ushort* rowp = feat + giA[rt] * 64 + quad * 8;
        aP[rt][0] = *(const short8*)(rowp);
        aP[rt][1] = *(const short8*)(rowp + 32);
      }
      if (k + 3 < KOFF) {
        #pragma unroll
        for (int rt = 0; rt < 4; ++rt) giB[rt] = nbr[roff[rt] + k + 3];
      }
      #pragma unroll
      for (int s = 0; s < 2; ++s)
        #pragma unroll
        for (int rt = 0; rt < 4; ++rt)
          #pragma unroll
          for (int ct = 0; ct < 4; ++ct)
            acc[rt][ct] = __builtin_amdgcn_mfma_f32_16x16x32_bf16(aQ[rt][s], b[s * 4 + ct], acc[rt][ct], 0, 0, 0);
    }
  }
  // ---- tail: k=26 consumes aP ----
  {
    short8 b[8];
    #pragma unroll
    for (int t = 0; t < 8; ++t) b[t] = wv[26 * 512 + t * 64 + lane];
    #pragma unroll
    for (int s = 0; s < 2; ++s)
      #pragma unroll
      for (int rt = 0; rt < 4; ++rt)
        #pragma unroll
        for (int ct = 0; ct < 4; ++ct)
          acc[rt][ct] = __builtin_amdgcn_mfma_f32_16x16x32_bf16(aP[rt][s], b[s * 4 + ct], acc[rt][ct], 0, 0, 0);
  }

  // Epilogue: acc[rt][ct][j] -> out[mw + rt*16 + quad*4 + j][ct*16 + lo]
  #pragma unroll
  for (int rt = 0; rt < 4; ++rt) {
    int rbase = mw + rt * 16 + quad * 4;
    #pragma unroll
    for (int ct = 0; ct < 4; ++ct) {
      int col = ct * 16 + lo;
      #pragma unroll
      for (int j = 0; j < 4; ++j) {
        int r = rbase + j;
        if (r < n) {
          float v = acc[rt][ct][j];
          if (MODE == 0) {
            v = v > 0.0f ? v : 0.0f;
            out_bf[r * 64 + col] = f2bf(v);
          } else {
            v += resid[r * 64 + col];
            v = v > 0.0f ? v : 0.0f;
            out_f[r * 64 + col] = v;
          }
        }
      }
    }
  }
}

extern "C" void kernel_launch(void* const* d_in, const int* in_sizes, int n_in,
                              void* d_out, int out_size, void* d_ws, size_t ws_size,
                              hipStream_t stream) {
  const float* x   = (const float*)d_in[0];
  const int*   nbr = (const int*)d_in[1];
  const float* W0  = (const float*)d_in[2];
  const float* W1  = (const float*)d_in[3];
  float* out = (float*)d_out;

  const int n    = NV;
  const int nc   = NV * 64;        // 9,600,000
  const int wtot = KOFF * 4096;    // 110,592

  ushort* xb  = (ushort*)d_ws;
  ushort* yb  = xb + nc;
  ushort* wp0 = yb + nc;
  ushort* wp1 = wp0 + wtot;

  cvt_x_kernel<<<(nc / 4 + 255) / 256, 256, 0, stream>>>(x, xb, nc);
  pack_w_kernel<<<(wtot + 255) / 256, 256, 0, stream>>>(W0, wp0, wtot);
  pack_w_kernel<<<(wtot + 255) / 256, 256, 0, stream>>>(W1, wp1, wtot);

  const int grid = (n + 63) / 64;  // 2344 one-wave blocks
  conv_kernel<0><<<grid, 64, 0, stream>>>(xb, nbr, wp0, nullptr, yb, nullptr, n);
  conv_kernel<1><<<grid, 64, 0, stream>>>(yb, nbr, wp1, x, nullptr, out, n);
}

// Round 5
// 322.259 us; speedup vs baseline: 1.0967x; 1.0967x over previous
//
#include <hip/hip_runtime.h>
#include <hip/hip_bf16.h>
#include <stdint.h>

// ResNetV1 sparse conv block, MI355X (gfx950).
// out = relu( conv(relu(conv(x,W0)), W1) + x ),  conv[n,d] = sum_k sum_c x[idx[n,k],c] * W[k,c,d]
// N=150000, K=27, C=64.
// R5: R3 structure (barrier-free, LDS-free, reg-gather, NO per-wave pipelining -- R4 showed
// it costs more occupancy than it hides latency) but with 2x the wave count:
//   - 32 rows/wave (rt=2) -> grid 4688 waves = 18.3/CU available (R3: 2344 = 9.2/CU cap).
//   - __launch_bounds__(64,4): 128-reg cap, ~105 used (a16+b32+acc32+addr), no spills.
//   - Gather-concurrency model: feat (19MB) >> 4MB/XCD L2, gathers miss to fabric at
//     ~400-900cyc; throughput scales with resident waves until the fabric ceiling.
//   - Prep fused into one launch.

typedef __attribute__((ext_vector_type(8))) short short8;
typedef __attribute__((ext_vector_type(4))) float f32x4;

#define NV 150000
#define KOFF 27

static __device__ __forceinline__ ushort f2bf(float f) {
  union { float f; uint32_t u; } v; v.f = f;
  uint32_t u = v.u;
  return (ushort)((u + 0x7fffu + ((u >> 16) & 1u)) >> 16);
}

// Fused prep: x -> bf16 (4/thread), then pack W0, W1 into B-fragment order.
// Pack map: flat = (((k*2+s)*4+ct)*64 + l)*8 + j <- W[k][c=s*32+(l>>4)*8+j][d=ct*16+(l&15)]
__global__ void prep_kernel(const float* __restrict__ x,
                            const float* __restrict__ W0,
                            const float* __restrict__ W1,
                            ushort* __restrict__ xb,
                            ushort* __restrict__ wp0,
                            ushort* __restrict__ wp1,
                            int nc4, int wtot) {
  int i = blockIdx.x * 256 + threadIdx.x;
  if (i < nc4) {
    float4 v = ((const float4*)x)[i];
    ushort4 o;
    o.x = f2bf(v.x); o.y = f2bf(v.y); o.z = f2bf(v.z); o.w = f2bf(v.w);
    ((ushort4*)xb)[i] = o;
    return;
  }
  int o = i - nc4;
  const float* W = W0;
  ushort* wp = wp0;
  if (o >= wtot) { o -= wtot; W = W1; wp = wp1; }
  if (o >= wtot) return;
  int j  = o & 7;
  int l  = (o >> 3) & 63;
  int ct = (o >> 9) & 3;
  int s  = (o >> 11) & 1;
  int k  = o >> 12;
  int c  = s * 32 + (l >> 4) * 8 + j;
  int d  = ct * 16 + (l & 15);
  wp[o] = f2bf(W[(k * 64 + c) * 64 + d]);
}

// One wave (64 threads) per 32 rows (2 x 16-row MFMA tiles).
// MODE 0: relu(conv) -> bf16. MODE 1: relu(conv+resid) -> fp32.
template <int MODE>
__global__ __launch_bounds__(64, 4) void conv_kernel(
    const ushort* __restrict__ feat,   // [N,64] bf16 bits
    const int*    __restrict__ nbr,    // [N,27]
    const ushort* __restrict__ wp,     // packed W, 27*4096 bf16
    const float*  __restrict__ resid,  // [N,64] fp32 (MODE 1)
    ushort*       __restrict__ out_bf, // MODE 0
    float*        __restrict__ out_f,  // MODE 1
    int n) {
  const int lane = threadIdx.x;       // 0..63
  const int quad = lane >> 4;
  const int lo   = lane & 15;
  const int mw   = blockIdx.x * 32;

  int roff[2];
  #pragma unroll
  for (int rt = 0; rt < 2; ++rt) {
    int r = mw + rt * 16 + lo;
    r = r < n ? r : n - 1;
    roff[rt] = r * KOFF;
  }

  const short8* wv = (const short8*)wp;  // frag t of offset k: wv[k*512 + t*64 + lane]

  f32x4 acc[2][4];
  #pragma unroll
  for (int rt = 0; rt < 2; ++rt)
    #pragma unroll
    for (int ct = 0; ct < 4; ++ct)
      acc[rt][ct] = (f32x4)0.0f;

  int gi[2];
  #pragma unroll
  for (int rt = 0; rt < 2; ++rt) gi[rt] = nbr[roff[rt]];

  #pragma unroll 1
  for (int k = 0; k < KOFF; ++k) {
    // Gather A fragments (random rows -> long latency; issue first).
    short8 a[2][2];
    #pragma unroll
    for (int rt = 0; rt < 2; ++rt) {
      const ushort* rowp = feat + gi[rt] * 64 + quad * 8;
      a[rt][0] = *(const short8*)(rowp);
      a[rt][1] = *(const short8*)(rowp + 32);
    }
    // Prefetch neighbor indices for k+1.
    if (k + 1 < KOFF) {
      #pragma unroll
      for (int rt = 0; rt < 2; ++rt) gi[rt] = nbr[roff[rt] + k + 1];
    }
    // B fragments (1 KB/instr coalesced, L2-hot: 8 KB/k shared by all waves).
    short8 b[8];
    #pragma unroll
    for (int t = 0; t < 8; ++t) b[t] = wv[k * 512 + t * 64 + lane];
    // 16 MFMAs.
    #pragma unroll
    for (int s = 0; s < 2; ++s)
      #pragma unroll
      for (int rt = 0; rt < 2; ++rt)
        #pragma unroll
        for (int ct = 0; ct < 4; ++ct)
          acc[rt][ct] = __builtin_amdgcn_mfma_f32_16x16x32_bf16(a[rt][s], b[s * 4 + ct], acc[rt][ct], 0, 0, 0);
  }

  // Epilogue: acc[rt][ct][j] -> out[mw + rt*16 + quad*4 + j][ct*16 + lo]
  #pragma unroll
  for (int rt = 0; rt < 2; ++rt) {
    int rbase = mw + rt * 16 + quad * 4;
    #pragma unroll
    for (int ct = 0; ct < 4; ++ct) {
      int col = ct * 16 + lo;
      #pragma unroll
      for (int j = 0; j < 4; ++j) {
        int r = rbase + j;
        if (r < n) {
          float v = acc[rt][ct][j];
          if (MODE == 0) {
            v = v > 0.0f ? v : 0.0f;
            out_bf[r * 64 + col] = f2bf(v);
          } else {
            v += resid[r * 64 + col];
            v = v > 0.0f ? v : 0.0f;
            out_f[r * 64 + col] = v;
          }
        }
      }
    }
  }
}

extern "C" void kernel_launch(void* const* d_in, const int* in_sizes, int n_in,
                              void* d_out, int out_size, void* d_ws, size_t ws_size,
                              hipStream_t stream) {
  const float* x   = (const float*)d_in[0];
  const int*   nbr = (const int*)d_in[1];
  const float* W0  = (const float*)d_in[2];
  const float* W1  = (const float*)d_in[3];
  float* out = (float*)d_out;

  const int n    = NV;
  const int nc   = NV * 64;        // 9,600,000
  const int nc4  = nc / 4;         // 2,400,000
  const int wtot = KOFF * 4096;    // 110,592

  ushort* xb  = (ushort*)d_ws;
  ushort* yb  = xb + nc;
  ushort* wp0 = yb + nc;
  ushort* wp1 = wp0 + wtot;

  const int prep_units = nc4 + 2 * wtot;
  prep_kernel<<<(prep_units + 255) / 256, 256, 0, stream>>>(x, W0, W1, xb, wp0, wp1, nc4, wtot);

  const int grid = (n + 31) / 32;  // 4688 one-wave blocks
  conv_kernel<0><<<grid, 64, 0, stream>>>(xb, nbr, wp0, nullptr, yb, nullptr, n);
  conv_kernel<1><<<grid, 64, 0, stream>>>(yb, nbr, wp1, x, nullptr, out, n);
}